// Round 1
// baseline (4554.716 us; speedup 1.0000x reference)
//
#include <hip/hip_runtime.h>
#include <math.h>

// ---------------- problem constants ----------------
#define NB     32
#define NPTS   8192
#define NZ     1024

// ---------------- tiling config --------------------
#define T_PTS          64          // points per tile (== lanes per wave)
#define TILES_PER_BLK  8           // points per block = 512
#define CHUNKS         16          // NPTS / (T_PTS*TILES_PER_BLK)
#define THREADS        512
#define NWAVE          8
#define STRIDE         256         // bf16 elements per LDS row (max channel count)
#define ROWBYTES       512         // STRIDE * 2

typedef unsigned short u16;
typedef unsigned int   u32;

__device__ __forceinline__ float bf2f(u16 u) {
    return __uint_as_float(((u32)u) << 16);
}
__device__ __forceinline__ u16 f2bf(float f) {
    u32 u = __float_as_uint(f);
    u = (u + 0x7fffu + ((u >> 16) & 1u)) >> 16;   // RNE
    return (u16)u;
}

__device__ __forceinline__ void unpack8(uint4 hv, float h[8]) {
    h[0] = bf2f((u16)(hv.x & 0xffffu)); h[1] = bf2f((u16)(hv.x >> 16));
    h[2] = bf2f((u16)(hv.y & 0xffffu)); h[3] = bf2f((u16)(hv.y >> 16));
    h[4] = bf2f((u16)(hv.z & 0xffffu)); h[5] = bf2f((u16)(hv.z >> 16));
    h[6] = bf2f((u16)(hv.w & 0xffffu)); h[7] = bf2f((u16)(hv.w >> 16));
}

// Generic pointwise layer: reads this thread's point-row (bf16), computes
// COUT/NWAVE outputs for this wave, writes back bf16 (optionally ReLU'd).
// W index (wave-uniform) -> scalar loads from L2.
template<int CIN, int COUT, bool RELU>
__device__ __forceinline__ void layer(const char* rowIn, char* rowOut, int swz,
                                      const float* __restrict__ W,
                                      const float* __restrict__ bias,
                                      int wave) {
    constexpr int OPW = COUT / NWAVE;       // outputs per wave (>= 8)
    const int ob0 = wave * OPW;
    for (int ob = 0; ob < OPW; ob += 8) {
        float acc[8];
        #pragma unroll
        for (int i = 0; i < 8; ++i) acc[i] = bias[ob0 + ob + i];
        #pragma unroll 2
        for (int cb = 0; cb < CIN; cb += 8) {
            uint4 hv = *(const uint4*)(rowIn + ((cb * 2) ^ swz));
            float h[8];
            unpack8(hv, h);
            #pragma unroll
            for (int i = 0; i < 8; ++i) {
                const float* wr = W + (ob0 + ob + i) * CIN + cb;
                #pragma unroll
                for (int j = 0; j < 8; ++j) acc[i] = fmaf(h[j], wr[j], acc[i]);
            }
        }
        u32 pk[4];
        #pragma unroll
        for (int i = 0; i < 4; ++i) {
            float a = acc[2 * i], b = acc[2 * i + 1];
            if (RELU) { a = fmaxf(a, 0.f); b = fmaxf(b, 0.f); }
            pk[i] = (u32)f2bf(a) | ((u32)f2bf(b) << 16);
        }
        *(uint4*)(rowOut + (((ob0 + ob) * 2) ^ swz)) = make_uint4(pk[0], pk[1], pk[2], pk[3]);
    }
}

// Layer 1: 3 -> 64, reads x directly from global (fp32), writes bf16 row.
__device__ __forceinline__ void layer1(const float* __restrict__ xb, int pt0,
                                       char* rowOut, int swz,
                                       const float* __restrict__ W1,
                                       const float* __restrict__ b1,
                                       int lane, int wave) {
    const float x0 = xb[0 * NPTS + pt0 + lane];
    const float x1 = xb[1 * NPTS + pt0 + lane];
    const float x2 = xb[2 * NPTS + pt0 + lane];
    const int ob0 = wave * 8;               // 64 / NWAVE
    float acc[8];
    #pragma unroll
    for (int i = 0; i < 8; ++i) {
        const int o = ob0 + i;
        float a = b1[o] + W1[o * 3 + 0] * x0 + W1[o * 3 + 1] * x1 + W1[o * 3 + 2] * x2;
        acc[i] = fmaxf(a, 0.f);
    }
    u32 pk[4];
    #pragma unroll
    for (int i = 0; i < 4; ++i)
        pk[i] = (u32)f2bf(acc[2 * i]) | ((u32)f2bf(acc[2 * i + 1]) << 16);
    *(uint4*)(rowOut + ((ob0 * 2) ^ swz)) = make_uint4(pk[0], pk[1], pk[2], pk[3]);
}

// Layer 5 (256 -> 1024) fused with max-pool: never materialized.
// Wave w covers z in [w*128, (w+1)*128). After each 8-z accumulation,
// wave-reduce max over the 64 points; lane (zl&63) keeps slot (zl>>6).
__device__ __forceinline__ void layer5(const char* rowIn, int swz,
                                       const float* __restrict__ W5,
                                       const float* __restrict__ b5,
                                       int lane, int wave, float rmax[2]) {
    const int z0 = wave * (NZ / NWAVE);     // wave*128
    #pragma unroll
    for (int slot = 0; slot < 2; ++slot) {
        for (int zb = slot * 64; zb < slot * 64 + 64; zb += 8) {
            float acc[8];
            #pragma unroll
            for (int i = 0; i < 8; ++i) acc[i] = b5[z0 + zb + i];
            #pragma unroll 2
            for (int cb = 0; cb < 256; cb += 8) {
                uint4 hv = *(const uint4*)(rowIn + ((cb * 2) ^ swz));
                float h[8];
                unpack8(hv, h);
                #pragma unroll
                for (int i = 0; i < 8; ++i) {
                    const float* wr = W5 + (z0 + zb + i) * 256 + cb;
                    #pragma unroll
                    for (int j = 0; j < 8; ++j) acc[i] = fmaf(h[j], wr[j], acc[i]);
                }
            }
            #pragma unroll
            for (int i = 0; i < 8; ++i) {
                float m = acc[i];
                #pragma unroll
                for (int off = 32; off >= 1; off >>= 1)
                    m = fmaxf(m, __shfl_xor(m, off, 64));
                if (lane == ((zb + i) & 63))
                    rmax[slot] = fmaxf(rmax[slot], m);
            }
        }
    }
}

extern "C" __global__ void __launch_bounds__(THREADS)
enc_main(const float* __restrict__ x,
         const float* __restrict__ W1, const float* __restrict__ b1,
         const float* __restrict__ W2, const float* __restrict__ b2,
         const float* __restrict__ W3, const float* __restrict__ b3,
         const float* __restrict__ W4, const float* __restrict__ b4,
         const float* __restrict__ W5, const float* __restrict__ b5,
         float* __restrict__ part) {
    __shared__ u16 bufA[T_PTS * STRIDE];    // 32 KB
    __shared__ u16 bufB[T_PTS * STRIDE];    // 32 KB  (total 64 KB -> 2 blocks/CU)

    const int bid   = blockIdx.x;
    const int b     = bid >> 4;             // batch
    const int chunk = bid & (CHUNKS - 1);
    const int lane  = threadIdx.x & 63;
    const int wave  = __builtin_amdgcn_readfirstlane((int)(threadIdx.x >> 6));
    const int swz   = (lane & 7) << 4;      // 16B-slot XOR swizzle -> conflict-floor b128

    char* rowA = (char*)bufA + lane * ROWBYTES;
    char* rowB = (char*)bufB + lane * ROWBYTES;
    const float* xb = x + (size_t)b * 3 * NPTS;

    float rmax[2] = { -1e38f, -1e38f };
    const int p0 = chunk * (T_PTS * TILES_PER_BLK);

    for (int it = 0; it < TILES_PER_BLK; ++it) {
        const int pt0 = p0 + it * T_PTS;
        layer1(xb, pt0, rowA, swz, W1, b1, lane, wave);
        __syncthreads();
        layer<64, 128, true>(rowA, rowB, swz, W2, b2, wave);
        __syncthreads();
        layer<128, 256, true>(rowB, rowA, swz, W3, b3, wave);
        __syncthreads();
        layer<256, 256, true>(rowA, rowB, swz, W4, b4, wave);
        __syncthreads();
        layer5(rowB, swz, W5, b5, lane, wave, rmax);
        // no barrier needed: next layer1 writes bufA only; the barrier after
        // layer1 orders all layer5 reads of bufB before layer2's writes.
    }

    // partial max for this block: part[b][chunk][z]
    float* dst = part + (size_t)bid * NZ;
    dst[wave * 128 +  0 + lane] = rmax[0];
    dst[wave * 128 + 64 + lane] = rmax[1];
}

extern "C" __global__ void enc_reduce(const float* __restrict__ part,
                                      float* __restrict__ out) {
    const int i = blockIdx.x * blockDim.x + threadIdx.x;
    if (i >= NB * NZ) return;
    const int b = i >> 10;
    const int z = i & (NZ - 1);
    float m = -1e38f;
    #pragma unroll
    for (int c = 0; c < CHUNKS; ++c)
        m = fmaxf(m, part[(size_t)(b * CHUNKS + c) * NZ + z]);
    out[i] = m;
}

extern "C" void kernel_launch(void* const* d_in, const int* in_sizes, int n_in,
                              void* d_out, int out_size, void* d_ws, size_t ws_size,
                              hipStream_t stream) {
    const float* x  = (const float*)d_in[0];
    const float* W1 = (const float*)d_in[1];  const float* b1 = (const float*)d_in[2];
    const float* W2 = (const float*)d_in[3];  const float* b2 = (const float*)d_in[4];
    const float* W3 = (const float*)d_in[5];  const float* b3 = (const float*)d_in[6];
    const float* W4 = (const float*)d_in[7];  const float* b4 = (const float*)d_in[8];
    const float* W5 = (const float*)d_in[9];  const float* b5 = (const float*)d_in[10];

    float* part = (float*)d_ws;               // [NB][CHUNKS][NZ] fp32 = 2 MB

    enc_main<<<dim3(NB * CHUNKS), dim3(THREADS), 0, stream>>>(
        x, W1, b1, W2, b2, W3, b3, W4, b4, W5, b5, part);

    const int tot = NB * NZ;
    enc_reduce<<<dim3((tot + 255) / 256), dim3(256), 0, stream>>>(part, (float*)d_out);
}

// Round 2
// 396.370 us; speedup vs baseline: 11.4911x; 11.4911x over previous
//
#include <hip/hip_runtime.h>
#include <math.h>

// ---------------- problem constants ----------------
#define NB      32
#define NPTS    8192
#define TOTPTS  (NB * NPTS)        // 262144 points
#define TILE    512                // points per block
#define TOTTILES (TOTPTS / TILE)   // 512

typedef unsigned short u16;
typedef unsigned int   u32;
typedef __attribute__((ext_vector_type(8))) short bf16x8;  // 8 bf16 = 4 VGPR
typedef __attribute__((ext_vector_type(4))) float f32x4;   // MFMA C/D

__device__ __forceinline__ u16 f2bf(float f) {
    u32 u = __float_as_uint(f);
    u = (u + 0x7fffu + ((u >> 16) & 1u)) >> 16;   // RNE
    return (u16)u;
}
__device__ __forceinline__ u32 pk2(float a, float b) {
    return (u32)f2bf(a) | ((u32)f2bf(b) << 16);
}
__device__ __forceinline__ f32x4 MFMA(bf16x8 a, bf16x8 b, f32x4 c) {
    return __builtin_amdgcn_mfma_f32_16x16x32_bf16(a, b, c, 0, 0, 0);
}

// Fragment conventions (mfma_f32_16x16x32_bf16):
//   A (16x32): lane holds A[row = l&15][k = (l>>4)*8 + j], j=0..7   -> weights W[o][c]
//   B (32x16): lane holds B[k = (l>>4)*8 + j][col = l&15]           -> H^T (col = point)
//   D (16x16): lane holds D[row = (l>>4)*4 + r][col = l&15]  [verified m89]
// So D gives each lane 4 CONSECUTIVE channels of ONE point -> 8B store.
// Packed H layout: frag(pf, kf) at byte ((pf*KF)+kf)*1024 + lane*16,
//   holding H[pf*16 + (l&15)][kf*32 + (l>>4)*8 + j] as bf16.
// Packed W layout: frag(nf, kf) at byte ((nf*KF)+kf)*1024 + lane*16,
//   holding W[nf*16 + (l&15)][kf*32 + (l>>4)*8 + j] as bf16.

// ---------------- weight prepack: fp32 [O][C] -> bf16 A-frags ----------------
// segments: W2 (8nf x 2kf = 16 frags), W3 (16x4=64), W4 (16x8=128), W5 (64x8=512)
__global__ __launch_bounds__(256) void k_pack(const float* __restrict__ W2,
        const float* __restrict__ W3, const float* __restrict__ W4,
        const float* __restrict__ W5, u16* __restrict__ dst) {
    int idx = blockIdx.x * 256 + threadIdx.x;         // (frag, lane)
    if (idx >= 720 * 64) return;
    int lane = idx & 63, fr = idx >> 6;
    const float* W; int C, frl;
    if (fr < 16)       { W = W2; C = 64;  frl = fr;       }
    else if (fr < 80)  { W = W3; C = 128; frl = fr - 16;  }
    else if (fr < 208) { W = W4; C = 256; frl = fr - 80;  }
    else               { W = W5; C = 256; frl = fr - 208; }
    int KF = C >> 5;
    int nf = frl / KF, kf = frl % KF;
    int o = nf * 16 + (lane & 15), c = kf * 32 + (lane >> 4) * 8;
    const float* s = W + (size_t)o * C + c;
    u32 out[4];
    #pragma unroll
    for (int j = 0; j < 4; ++j) out[j] = pk2(s[2 * j], s[2 * j + 1]);
    *(uint4*)((char*)dst + (size_t)idx * 16) = make_uint4(out[0], out[1], out[2], out[3]);
}

// ---------------- K_A: L1 (VALU 3->64) + L2 (MFMA 64->128) ----------------
__global__ __launch_bounds__(512) void k_a(const float* __restrict__ x,
        const float* __restrict__ W1, const float* __restrict__ b1,
        const u16* __restrict__ W2p, const float* __restrict__ b2,
        u16* __restrict__ H2p, int pt0) {
    __shared__ u16 H1[TILE * 64];                     // 64 KB, row = 128 B
    const int tid = threadIdx.x, lane = tid & 63, w = tid >> 6;
    const int l15 = lane & 15, q = lane >> 4;
    const int t = blockIdx.x;
    const size_t ptbase = (size_t)pt0 + (size_t)t * TILE;
    const int b  = (int)(ptbase >> 13);               // batch (tile never crosses)
    const int nn = (int)(ptbase & 8191);

    // L1: lane <-> point (w*64 + lane); write bf16 row to LDS (XOR-swizzled 16B slots)
    const int myp = w * 64 + lane;
    const float* xb = x + (size_t)b * 3 * NPTS + nn + myp;
    const float x0 = xb[0], x1 = xb[NPTS], x2 = xb[2 * NPTS];
    {
        char* rowp = (char*)H1 + myp * 128;
        const int swz = (myp & 7) << 4;
        #pragma unroll
        for (int cb = 0; cb < 64; cb += 8) {
            u32 pkv[4];
            #pragma unroll
            for (int i = 0; i < 4; ++i) {
                int o0 = cb + 2 * i, o1 = o0 + 1;
                float a0 = fmaxf(b1[o0] + W1[o0*3]*x0 + W1[o0*3+1]*x1 + W1[o0*3+2]*x2, 0.f);
                float a1 = fmaxf(b1[o1] + W1[o1*3]*x0 + W1[o1*3+1]*x1 + W1[o1*3+2]*x2, 0.f);
                pkv[i] = pk2(a0, a1);
            }
            *(uint4*)(rowp + ((cb * 2) ^ swz)) = make_uint4(pkv[0], pkv[1], pkv[2], pkv[3]);
        }
    }
    __syncthreads();

    // L2: wave owns 4 point-frags (w*4+g); B-frags from LDS, A-frags from packed W2 (L2-cached)
    bf16x8 hb[2][4];
    #pragma unroll
    for (int kf = 0; kf < 2; ++kf)
        #pragma unroll
        for (int g = 0; g < 4; ++g) {
            int r2 = w * 64 + g * 16 + l15;
            hb[kf][g] = *(const bf16x8*)((const char*)H1 + r2 * 128 +
                                         ((kf * 64 + q * 16) ^ ((r2 & 7) << 4)));
        }
    const int qterm = ((q >> 1) * 16 + l15) * 16 + (q & 1) * 8;
    for (int nf = 0; nf < 8; ++nf) {
        f32x4 acc[4];
        f32x4 bv = *(const f32x4*)(b2 + nf * 16 + q * 4);
        #pragma unroll
        for (int g = 0; g < 4; ++g) acc[g] = bv;
        #pragma unroll
        for (int kf = 0; kf < 2; ++kf) {
            bf16x8 A = *(const bf16x8*)((const char*)W2p + (size_t)(nf * 2 + kf) * 1024 + lane * 16);
            #pragma unroll
            for (int g = 0; g < 4; ++g) acc[g] = MFMA(A, hb[kf][g], acc[g]);
        }
        #pragma unroll
        for (int g = 0; g < 4; ++g) {                 // ReLU + pack + packed store (KF_out = 4)
            size_t pfc = (size_t)t * 32 + w * 4 + g;
            u32 d0 = pk2(fmaxf(acc[g][0], 0.f), fmaxf(acc[g][1], 0.f));
            u32 d1 = pk2(fmaxf(acc[g][2], 0.f), fmaxf(acc[g][3], 0.f));
            *(uint2*)((char*)H2p + (pfc * 4 + (nf >> 1)) * 1024 + (nf & 1) * 512 + qterm)
                = make_uint2(d0, d1);
        }
    }
}

// ---------------- K_MID: generic MFMA layer CIN=KF*32 -> 256, ReLU ----------------
template<int KF>
__global__ __launch_bounds__(512) void k_mid(const u16* __restrict__ Hin,
        const u16* __restrict__ Wp, const float* __restrict__ bias,
        u16* __restrict__ Hout) {
    __shared__ u16 ldsW[8 * KF * 512];                // 8 nf-frags/chunk: 32/64 KB
    constexpr int CB = 8 * KF * 1024;                 // chunk bytes
    constexpr int NSTG = CB / (512 * 16);             // uint4 per thread
    const int tid = threadIdx.x, lane = tid & 63, w = tid >> 6;
    const int l15 = lane & 15, q = lane >> 4;
    const int t = blockIdx.x;
    const int qterm = ((q >> 1) * 16 + l15) * 16 + (q & 1) * 8;

    bf16x8 hb[KF][4];                                 // wave's H-panel (B-operand)
    #pragma unroll
    for (int kf = 0; kf < KF; ++kf)
        #pragma unroll
        for (int g = 0; g < 4; ++g) {
            size_t pf = (size_t)t * 32 + w * 4 + g;
            hb[kf][g] = *(const bf16x8*)((const char*)Hin + (pf * KF + kf) * 1024 + lane * 16);
        }
    uint4 stg[NSTG];
    #pragma unroll
    for (int i = 0; i < NSTG; ++i)
        stg[i] = *(const uint4*)((const char*)Wp + i * 8192 + tid * 16);

    for (int c = 0; c < 2; ++c) {                     // 2 chunks x 8 nf = 16 nf (COUT=256)
        __syncthreads();
        #pragma unroll
        for (int i = 0; i < NSTG; ++i)
            *(uint4*)((char*)ldsW + i * 8192 + tid * 16) = stg[i];
        __syncthreads();
        if (c == 0) {                                 // prefetch chunk 1 under compute
            #pragma unroll
            for (int i = 0; i < NSTG; ++i)
                stg[i] = *(const uint4*)((const char*)Wp + CB + i * 8192 + tid * 16);
        }
        for (int a = 0; a < 8; ++a) {
            const int nf = c * 8 + a;
            f32x4 acc[4];
            f32x4 bv = *(const f32x4*)(bias + nf * 16 + q * 4);
            #pragma unroll
            for (int g = 0; g < 4; ++g) acc[g] = bv;
            #pragma unroll
            for (int kf = 0; kf < KF; ++kf) {
                bf16x8 A = *(const bf16x8*)((const char*)ldsW + (size_t)(a * KF + kf) * 1024 + lane * 16);
                #pragma unroll
                for (int g = 0; g < 4; ++g) acc[g] = MFMA(A, hb[kf][g], acc[g]);
            }
            #pragma unroll
            for (int g = 0; g < 4; ++g) {             // KF_out = 8 (COUT 256)
                size_t pfc = (size_t)t * 32 + w * 4 + g;
                u32 d0 = pk2(fmaxf(acc[g][0], 0.f), fmaxf(acc[g][1], 0.f));
                u32 d1 = pk2(fmaxf(acc[g][2], 0.f), fmaxf(acc[g][3], 0.f));
                *(uint2*)((char*)Hout + (pfc * 8 + (nf >> 1)) * 1024 + (nf & 1) * 512 + qterm)
                    = make_uint2(d0, d1);
            }
        }
    }
}

// ---------------- K_L5: 256 -> 1024 fused with max-pool ----------------
__global__ __launch_bounds__(512) void k_l5(const u16* __restrict__ Hin,
        const u16* __restrict__ Wp, const float* __restrict__ bias,
        float* __restrict__ parts, int tile0) {
    __shared__ u16 ldsW[4 * 8 * 512];                 // 4 nf x 8 kf = 32 KB
    const int tid = threadIdx.x, lane = tid & 63, w = tid >> 6;
    const int l15 = lane & 15, q = lane >> 4;
    const int t = blockIdx.x;

    bf16x8 hb[8][4];
    #pragma unroll
    for (int kf = 0; kf < 8; ++kf)
        #pragma unroll
        for (int g = 0; g < 4; ++g) {
            size_t pf = (size_t)t * 32 + w * 4 + g;
            hb[kf][g] = *(const bf16x8*)((const char*)Hin + (pf * 8 + kf) * 1024 + lane * 16);
        }
    float rmax[16];
    #pragma unroll
    for (int i = 0; i < 16; ++i) rmax[i] = -3.402823466e38f;

    uint4 stg[4];
    #pragma unroll
    for (int i = 0; i < 4; ++i)
        stg[i] = *(const uint4*)((const char*)Wp + i * 8192 + tid * 16);

    #pragma unroll
    for (int cc = 0; cc < 4; ++cc) {                  // static: rmax index = cc*4+r
        for (int c2 = 0; c2 < 4; ++c2) {
            const int c = cc * 4 + c2;                // chunk = 4 nf (32 KB)
            __syncthreads();
            #pragma unroll
            for (int i = 0; i < 4; ++i)
                *(uint4*)((char*)ldsW + i * 8192 + tid * 16) = stg[i];
            __syncthreads();
            if (c < 15) {
                #pragma unroll
                for (int i = 0; i < 4; ++i)
                    stg[i] = *(const uint4*)((const char*)Wp + (size_t)(c + 1) * 32768 + i * 8192 + tid * 16);
            }
            for (int a = 0; a < 4; ++a) {
                const int nf = c * 4 + a;
                f32x4 acc[4];
                f32x4 bv = *(const f32x4*)(bias + nf * 16 + q * 4);
                #pragma unroll
                for (int g = 0; g < 4; ++g) acc[g] = bv;
                #pragma unroll
                for (int kf = 0; kf < 8; ++kf) {
                    bf16x8 A = *(const bf16x8*)((const char*)ldsW + (size_t)(a * 8 + kf) * 1024 + lane * 16);
                    #pragma unroll
                    for (int g = 0; g < 4; ++g) acc[g] = MFMA(A, hb[kf][g], acc[g]);
                }
                // max over wave's 64 points: over g, then over the 16 point-lanes of q-group
                const bool keep = (l15 == c2 * 4 + a);   // nf & 15
                #pragma unroll
                for (int r = 0; r < 4; ++r) {
                    float m = fmaxf(fmaxf(acc[0][r], acc[1][r]), fmaxf(acc[2][r], acc[3][r]));
                    m = fmaxf(m, __shfl_xor(m, 1, 64));
                    m = fmaxf(m, __shfl_xor(m, 2, 64));
                    m = fmaxf(m, __shfl_xor(m, 4, 64));
                    m = fmaxf(m, __shfl_xor(m, 8, 64));
                    rmax[cc * 4 + r] = keep ? fmaxf(rmax[cc * 4 + r], m) : rmax[cc * 4 + r];
                }
            }
        }
    }
    // lane (q,l15) holds z = ((i>>2)*16 + l15)*16 + q*4 + (i&3), i=0..15 (bijective over 1024)
    float* dst = parts + ((size_t)(tile0 + t) * 8 + w) * 1024;
    #pragma unroll
    for (int i = 0; i < 16; ++i) {
        int z = ((i >> 2) * 16 + l15) * 16 + q * 4 + (i & 3);
        dst[z] = rmax[i];
    }
}

// ---------------- final reduce: 512 tiles x 8 waves -> [32][1024] ----------------
__global__ __launch_bounds__(256) void k_red(const float* __restrict__ parts,
                                             float* __restrict__ out) {
    int i = blockIdx.x * 256 + threadIdx.x;           // 32768
    int b = i >> 10, z = i & 1023;
    float m = -3.402823466e38f;
    for (int r = 0; r < 128; ++r)                     // 16 tiles * 8 waves per batch
        m = fmaxf(m, parts[((size_t)b * 128 + r) * 1024 + z]);
    out[i] = m;
}

extern "C" void kernel_launch(void* const* d_in, const int* in_sizes, int n_in,
                              void* d_out, int out_size, void* d_ws, size_t ws_size,
                              hipStream_t stream) {
    const float* x  = (const float*)d_in[0];
    const float* W1 = (const float*)d_in[1]; const float* b1 = (const float*)d_in[2];
    const float* W2 = (const float*)d_in[3]; const float* b2 = (const float*)d_in[4];
    const float* W3 = (const float*)d_in[5]; const float* b3 = (const float*)d_in[6];
    const float* W4 = (const float*)d_in[7]; const float* b4 = (const float*)d_in[8];
    const float* W5 = (const float*)d_in[9]; const float* b5 = (const float*)d_in[10];

    // ws layout: packed weights (768 KB) | partials (16 MB) | HA | HB
    u16* wsW = (u16*)d_ws;
    const u16* W2p = (const u16*)((char*)d_ws + 0);
    const u16* W3p = (const u16*)((char*)d_ws + 16 * 1024);
    const u16* W4p = (const u16*)((char*)d_ws + 80 * 1024);
    const u16* W5p = (const u16*)((char*)d_ws + 208 * 1024);
    float* parts   = (float*)((char*)d_ws + 786432);
    char* Hbase    = (char*)d_ws + 786432 + 16777216;

    int NCH = 2;                                      // batch-chunking for ws budget
    while (NCH < 32) {
        size_t npc = (size_t)TOTPTS / NCH;
        if (786432 + 16777216 + npc * 1024 <= ws_size) break;
        NCH *= 2;
    }
    const size_t npts_c = (size_t)TOTPTS / NCH;
    char* HA = Hbase;                                 // H3 (512 B/pt)
    char* HB = Hbase + npts_c * 512;                  // H2 (256 B/pt) then H4 (512 B/pt)

    k_pack<<<dim3(180), dim3(256), 0, stream>>>(W2, W3, W4, W5, wsW);

    const int ntc = (int)(npts_c / TILE);
    for (int c = 0; c < NCH; ++c) {
        int pt0 = (int)(c * npts_c);
        int tile0 = pt0 / TILE;
        k_a<<<dim3(ntc), dim3(512), 0, stream>>>(x, W1, b1, W2p, b2, (u16*)HB, pt0);
        k_mid<4><<<dim3(ntc), dim3(512), 0, stream>>>((const u16*)HB, W3p, b3, (u16*)HA);
        k_mid<8><<<dim3(ntc), dim3(512), 0, stream>>>((const u16*)HA, W4p, b4, (u16*)HB);
        k_l5<<<dim3(ntc), dim3(512), 0, stream>>>((const u16*)HB, W5p, b5, parts, tile0);
    }
    k_red<<<dim3(128), dim3(256), 0, stream>>>(parts, (float*)d_out);
}